// Round 1
// baseline (107.645 us; speedup 1.0000x reference)
//
#include <hip/hip_runtime.h>
#include <hip/hip_bf16.h>
#include <cstdint>

#define HIDDEN 128
#define POOL   64
#define GRIDG  4
#define GG     16          // GRIDG*GRIDG
#define NBHD   2.0f
#define PEDS   64
#define NCOL   (GG * POOL) // 1024 = hw columns

typedef unsigned short u16;
typedef __attribute__((ext_vector_type(8))) short bf16x8;
typedef __attribute__((ext_vector_type(4))) float f32x4;

// ---- bf16 helpers (manual, avoids __hip_bfloat16 class in unions) ----
__device__ __forceinline__ u16 f2bf(float f) {
    uint32_t u = __float_as_uint(f);
    u += 0x7fffu + ((u >> 16) & 1u);   // round-to-nearest-even
    return (u16)(u >> 16);
}
__device__ __forceinline__ uint32_t pack2bf(float a, float b) {
    return (uint32_t)f2bf(a) | ((uint32_t)f2bf(b) << 16);
}
__device__ __forceinline__ float bflo(uint32_t u) { return __uint_as_float(u << 16); }
__device__ __forceinline__ float bfhi(uint32_t u) { return __uint_as_float(u & 0xffff0000u); }

// =====================================================================
// K1: cast hidden -> bf16 (swizzled) and build WtT[n][k] bf16 (swizzled)
//   swizzle: within each 128-elem row, 16B chunk t stored at t ^ (row & 15)
// =====================================================================
__global__ __launch_bounds__(256) void prep_kernel(
    const float* __restrict__ h, const float* __restrict__ w,
    u16* __restrict__ hb, u16* __restrict__ wt, int nch_h, int nch_tot)
{
    int c = blockIdx.x * 256 + threadIdx.x;
    if (c >= nch_tot) return;
    uint32_t u0, u1, u2, u3;
    if (c < nch_h) {
        int m = c >> 4, t = c & 15;
        const float* src = h + ((size_t)m << 7) + t * 8;
        u0 = pack2bf(src[0], src[1]);
        u1 = pack2bf(src[2], src[3]);
        u2 = pack2bf(src[4], src[5]);
        u3 = pack2bf(src[6], src[7]);
        uint4* dst = (uint4*)(hb + ((size_t)m << 7) + ((size_t)(t ^ (m & 15)) << 3));
        *dst = make_uint4(u0, u1, u2, u3);
    } else {
        int cc = c - nch_h;
        int n = cc >> 4, t = cc & 15;
        int g = n >> 6, p = n & 63;
        // WtT[n][k] = w[(g*128 + k)*64 + p]
        const float* src = w + (size_t)g * (HIDDEN * POOL) + p;
        int k0 = t * 8;
        u0 = pack2bf(src[(size_t)(k0 + 0) * 64], src[(size_t)(k0 + 1) * 64]);
        u1 = pack2bf(src[(size_t)(k0 + 2) * 64], src[(size_t)(k0 + 3) * 64]);
        u2 = pack2bf(src[(size_t)(k0 + 4) * 64], src[(size_t)(k0 + 5) * 64]);
        u3 = pack2bf(src[(size_t)(k0 + 6) * 64], src[(size_t)(k0 + 7) * 64]);
        uint4* dst = (uint4*)(wt + ((size_t)n << 7) + ((size_t)(t ^ (n & 15)) << 3));
        *dst = make_uint4(u0, u1, u2, u3);
    }
}

// =====================================================================
// K2: hw[m,n] = sum_k hb[m,k] * WtT[n,k]   (M=total, N=1024, K=128)
//   128x128 tile per block, 4 waves in 2x2, 16x16x32 bf16 MFMA, K done
//   in 4 steps from a single LDS stage. Output bf16 row-major (unswizzled).
// =====================================================================
__global__ __launch_bounds__(256, 2) void gemm_kernel(
    const u16* __restrict__ A, const u16* __restrict__ Bt, u16* __restrict__ C)
{
    __shared__ u16 As[128 * 128];
    __shared__ u16 Bs[128 * 128];
    const int tid = threadIdx.x;
    const int nt = blockIdx.x, mt = blockIdx.y;

    // stage: both tiles are fully contiguous 32KB blocks (K=128 = full row)
    const u16* ga = A  + ((size_t)mt << 14);
    const u16* gb = Bt + ((size_t)nt << 14);
#pragma unroll
    for (int it = 0; it < 8; ++it) {
        int off = (it * 256 + tid) * 8;   // in u16 units: 8 u16 = 16B per lane
        __builtin_amdgcn_global_load_lds(
            (const __attribute__((address_space(1))) uint32_t*)(ga + off),
            (__attribute__((address_space(3))) uint32_t*)(As + off), 16, 0, 0);
    }
#pragma unroll
    for (int it = 0; it < 8; ++it) {
        int off = (it * 256 + tid) * 8;
        __builtin_amdgcn_global_load_lds(
            (const __attribute__((address_space(1))) uint32_t*)(gb + off),
            (__attribute__((address_space(3))) uint32_t*)(Bs + off), 16, 0, 0);
    }
    asm volatile("s_waitcnt vmcnt(0)" ::: "memory");
    __syncthreads();

    const int lane = tid & 63;
    const int l15  = lane & 15;
    const int q    = lane >> 4;
    const int wv   = tid >> 6;
    const int m0   = (wv & 1) * 64;
    const int n0   = (wv >> 1) * 64;

    f32x4 acc[4][4];
#pragma unroll
    for (int a = 0; a < 4; ++a)
#pragma unroll
        for (int b = 0; b < 4; ++b) acc[a][b] = (f32x4){0.f, 0.f, 0.f, 0.f};

#pragma unroll
    for (int s = 0; s < 4; ++s) {
        const int chunk = ((s * 4 + q) ^ l15) * 8;   // de-swizzle
        bf16x8 af[4], bf[4];
#pragma unroll
        for (int mi = 0; mi < 4; ++mi)
            af[mi] = *(const bf16x8*)&As[(m0 + mi * 16 + l15) * 128 + chunk];
#pragma unroll
        for (int ni = 0; ni < 4; ++ni)
            bf[ni] = *(const bf16x8*)&Bs[(n0 + ni * 16 + l15) * 128 + chunk];
#pragma unroll
        for (int mi = 0; mi < 4; ++mi)
#pragma unroll
            for (int ni = 0; ni < 4; ++ni)
                acc[mi][ni] = __builtin_amdgcn_mfma_f32_16x16x32_bf16(
                    af[mi], bf[ni], acc[mi][ni], 0, 0, 0);
    }

    // epilogue: C/D layout col=lane&15, row=(lane>>4)*4+reg (m89/m91)
    u16* cb = C + ((size_t)mt * 128) * NCOL + (size_t)nt * 128;
#pragma unroll
    for (int mi = 0; mi < 4; ++mi)
#pragma unroll
        for (int r = 0; r < 4; ++r) {
            size_t row = (size_t)(m0 + mi * 16 + q * 4 + r);
#pragma unroll
            for (int ni = 0; ni < 4; ++ni) {
                int col = n0 + ni * 16 + l15;
                cb[row * NCOL + col] = f2bf(acc[mi][ni][r]);
            }
        }
}

// =====================================================================
// K3: out[i,c] = bias[c] + sum_j (mask) hw[j, g(i,j)*64 + c]
//   one block per (scene, channel-half); gidx table in LDS (exact
//   replica of reference mask/floor/clip in fp32)
// =====================================================================
__global__ __launch_bounds__(256) void pool_kernel(
    const float* __restrict__ pos, const u16* __restrict__ hw,
    const float* __restrict__ bias, float* __restrict__ out)
{
    const int s    = blockIdx.x;
    const int half = blockIdx.y;
    const int tid  = threadIdx.x;
    __shared__ float px[PEDS], py[PEDS];
    __shared__ signed char gidx[PEDS * PEDS];

    if (tid < PEDS) {
        px[tid] = pos[((size_t)s * PEDS + tid) * 2 + 0];
        py[tid] = pos[((size_t)s * PEDS + tid) * 2 + 1];
    }
    __syncthreads();

    const float scale = (float)GRIDG / (2.0f * NBHD);
#pragma unroll
    for (int u = 0; u < 16; ++u) {
        int e  = tid * 16 + u;
        int ii = e >> 6, jj = e & 63;
        float rx = px[jj] - px[ii];
        float ry = py[jj] - py[ii];
        int g = -1;
        if ((ii != jj) && (fabsf(rx) <= NBHD) && (fabsf(ry) <= NBHD)) {
            int gx = (int)floorf((rx + NBHD) * scale); gx = min(max(gx, 0), GRIDG - 1);
            int gy = (int)floorf((ry + NBHD) * scale); gy = min(max(gy, 0), GRIDG - 1);
            g = gy * GRIDG + gx;
        }
        gidx[e] = (signed char)g;
    }
    __syncthreads();

    const int i  = tid >> 2;                    // ped 0..63
    const int cb = half * 32 + (tid & 3) * 8;   // 8 channels per thread
    const u16* base = hw + ((size_t)s * PEDS) * NCOL;
    float a0 = 0.f, a1 = 0.f, a2 = 0.f, a3 = 0.f, a4 = 0.f, a5 = 0.f, a6 = 0.f, a7 = 0.f;
#pragma unroll 8
    for (int j = 0; j < PEDS; ++j) {
        int g = gidx[i * 64 + j];
        if (g >= 0) {
            uint4 r = *(const uint4*)(base + (size_t)j * NCOL + g * 64 + cb);
            a0 += bflo(r.x); a1 += bfhi(r.x);
            a2 += bflo(r.y); a3 += bfhi(r.y);
            a4 += bflo(r.z); a5 += bfhi(r.z);
            a6 += bflo(r.w); a7 += bfhi(r.w);
        }
    }
    float* o = out + ((size_t)s * PEDS + i) * POOL + cb;
    o[0] = a0 + bias[cb + 0]; o[1] = a1 + bias[cb + 1];
    o[2] = a2 + bias[cb + 2]; o[3] = a3 + bias[cb + 3];
    o[4] = a4 + bias[cb + 4]; o[5] = a5 + bias[cb + 5];
    o[6] = a6 + bias[cb + 6]; o[7] = a7 + bias[cb + 7];
}

extern "C" void kernel_launch(void* const* d_in, const int* in_sizes, int n_in,
                              void* d_out, int out_size, void* d_ws, size_t ws_size,
                              hipStream_t stream) {
    const float* h    = (const float*)d_in[0];
    const float* pos  = (const float*)d_in[1];
    const float* w    = (const float*)d_in[2];
    const float* bias = (const float*)d_in[3];
    float* out = (float*)d_out;

    const int total = in_sizes[0] / HIDDEN;   // 16384 rows
    const int B     = total / PEDS;           // 256 scenes

    // workspace layout (bf16): hb [total,128] | WtT [1024,128] | hw [total,1024]
    u16* hb = (u16*)d_ws;
    u16* wt = hb + (size_t)total * HIDDEN;
    u16* hw = wt + (size_t)NCOL * HIDDEN;

    const int nch_h   = total * (HIDDEN / 8);
    const int nch_tot = nch_h + NCOL * (HIDDEN / 8);
    hipLaunchKernelGGL(prep_kernel, dim3((nch_tot + 255) / 256), dim3(256), 0, stream,
                       h, w, hb, wt, nch_h, nch_tot);
    hipLaunchKernelGGL(gemm_kernel, dim3(NCOL / 128, total / 128), dim3(256), 0, stream,
                       hb, wt, hw);
    hipLaunchKernelGGL(pool_kernel, dim3(B, 2), dim3(256), 0, stream,
                       pos, hw, bias, out);
}

// Round 2
// 81.929 us; speedup vs baseline: 1.3139x; 1.3139x over previous
//
#include <hip/hip_runtime.h>
#include <cstdint>

#define HIDDEN 128
#define POOL   64
#define GRIDG  4
#define NBHD   2.0f
#define PEDS   64

typedef unsigned short u16;
typedef unsigned int   u32;
typedef __attribute__((ext_vector_type(8))) short bf16x8;
typedef __attribute__((ext_vector_type(4))) float f32x4;

__device__ __forceinline__ u16 f2bf(float f) {
    u32 u = __float_as_uint(f);
    u += 0x7fffu + ((u >> 16) & 1u);   // RNE
    return (u16)(u >> 16);
}
__device__ __forceinline__ u32 pack2bf(float a, float b) {
    return (u32)f2bf(a) | ((u32)f2bf(b) << 16);
}
__device__ __forceinline__ float bflo(u32 u){ return __uint_as_float(u << 16); }
__device__ __forceinline__ float bfhi(u32 u){ return __uint_as_float(u & 0xffff0000u); }

// One block per scene. LDS (64 KB exact):
//   [0      : 8192 ) u16  hA   : h bf16, 64 rows x 128 k, XOR-chunk swizzle
//                          (overlaid by gidx bytes [64x64] after A-frags read)
//   [8192   : 16384) u16  wS   : Wg bf16, 64 rows(c) x 128 k, same swizzle
//   [16384  : 32768) u16  hwS  : 4 slots x 64 j x 64 c, oct XOR slot swizzle
//                          (word 0 doubles as used-g mask before first epilogue)
__global__ __launch_bounds__(256) void social_pool_fused(
    const float* __restrict__ h, const float* __restrict__ pos,
    const float* __restrict__ w, const float* __restrict__ bias,
    float* __restrict__ out)
{
    __shared__ u16 LDS[32768];
    const int s    = blockIdx.x;
    const int tid  = threadIdx.x;
    const int lane = tid & 63;
    const int wv   = tid >> 6;
    const int l15  = lane & 15;
    const int q    = lane >> 4;

    // ---- positions: lane l holds ped l (each wave redundantly) ----
    float px = pos[((size_t)s * PEDS + lane) * 2 + 0];
    float py = pos[((size_t)s * PEDS + lane) * 2 + 1];

    // ---- h loads issued early: thread = (row=tid>>2, quarter=tid&3) ----
    const int hrow = tid >> 2;
    const int hq   = tid & 3;
    const float* hsrc = h + ((size_t)s * PEDS + hrow) * HIDDEN + hq * 32;
    float4 hv[8];
#pragma unroll
    for (int e = 0; e < 8; ++e) hv[e] = ((const float4*)hsrc)[e];

    // ---- gidx for this thread's 16 pairs: i = tid>>2, j = (tid&3)*16+u ----
    const int i  = tid >> 2;
    const int jo = tid & 3;
    const float pxi = __shfl(px, i);
    const float pyi = __shfl(py, i);
    u32 gw[4] = {0u, 0u, 0u, 0u};
    unsigned um = 0u;
    const float scale = (float)GRIDG / (2.0f * NBHD);
#pragma unroll
    for (int u = 0; u < 16; ++u) {
        int j = jo * 16 + u;
        float rx = __shfl(px, j) - pxi;
        float ry = __shfl(py, j) - pyi;
        u32 gb = 0xffu;
        if ((i != j) && (fabsf(rx) <= NBHD) && (fabsf(ry) <= NBHD)) {
            int gx = (int)floorf((rx + NBHD) * scale); gx = min(max(gx, 0), GRIDG - 1);
            int gy = (int)floorf((ry + NBHD) * scale); gy = min(max(gy, 0), GRIDG - 1);
            int g = gy * GRIDG + gx;
            gb = (u32)g;
            um |= 1u << g;
        }
        gw[u >> 2] |= gb << ((u & 3) * 8);
    }

    unsigned* maskPtr = (unsigned*)&LDS[16384];
    if (tid == 0) *maskPtr = 0u;

    // ---- convert h -> hA (swizzled: chunk c stored at c ^ (row&15)) ----
#pragma unroll
    for (int cc = 0; cc < 4; ++cc) {
        float4 f0 = hv[cc * 2], f1 = hv[cc * 2 + 1];
        u32 p0 = pack2bf(f0.x, f0.y);
        u32 p1 = pack2bf(f0.z, f0.w);
        u32 p2 = pack2bf(f1.x, f1.y);
        u32 p3 = pack2bf(f1.z, f1.w);
        *(uint4*)&LDS[hrow * 128 + (((hq * 4 + cc) ^ (hrow & 15)) << 3)] =
            make_uint4(p0, p1, p2, p3);
    }
    __syncthreads();                       // B1: hA complete, mask zeroed

    atomicOr(maskPtr, um);

    // ---- A fragments: wave wv owns j-rows wv*16..wv*16+15, all K ----
    bf16x8 af[4];
    const int arow = wv * 16 + l15;
#pragma unroll
    for (int st4 = 0; st4 < 4; ++st4)
        af[st4] = *(const bf16x8*)&LDS[arow * 128 + (((st4 * 4 + q) ^ l15) << 3)];

    __syncthreads();                       // B2: mask reduced, A-frags read
    const unsigned mask = *maskPtr;

    // ---- overlay gidx bytes into hA region: byte offset tid*16 = i*64+jo*16 ----
    *(uint4*)&LDS[tid * 8] = make_uint4(gw[0], gw[1], gw[2], gw[3]);
    __syncthreads();                       // B2b: gidx visible, mask read by all

    // ---- own gidx row i into registers ----
    u32 gr[16];
#pragma unroll
    for (int p = 0; p < 4; ++p) {
        uint4 qv = *(const uint4*)&LDS[i * 32 + p * 8];
        gr[p * 4 + 0] = qv.x; gr[p * 4 + 1] = qv.y;
        gr[p * 4 + 2] = qv.z; gr[p * 4 + 3] = qv.w;
    }

    float a0[8], a1[8];
#pragma unroll
    for (int e = 0; e < 8; ++e) { a0[e] = 0.f; a1[e] = 0.f; }

    // ==== batches of up to 4 used grid cells ====
    unsigned rem = mask;
    int bi = 0;
    while (rem) {
        for (int t = 0; t < 4; ++t) {
            if (!rem) break;               // uniform across block
            int g = __ffs(rem) - 1;
            rem &= rem - 1u;

            // ---- stage Wg -> wS (fp32 gather, convert, swizzled write) ----
            {
                const int r_ = lane;       // output channel c
                const int kq = wv;         // k-quarter
                const float* src = w + ((size_t)g * 128 + kq * 32) * 64 + r_;
                float v[32];
#pragma unroll
                for (int e = 0; e < 32; ++e) v[e] = src[(size_t)e * 64];
#pragma unroll
                for (int cc = 0; cc < 4; ++cc) {
                    u32 p0 = pack2bf(v[cc * 8 + 0], v[cc * 8 + 1]);
                    u32 p1 = pack2bf(v[cc * 8 + 2], v[cc * 8 + 3]);
                    u32 p2 = pack2bf(v[cc * 8 + 4], v[cc * 8 + 5]);
                    u32 p3 = pack2bf(v[cc * 8 + 6], v[cc * 8 + 7]);
                    *(uint4*)&LDS[8192 + r_ * 128 + (((kq * 4 + cc) ^ (r_ & 15)) << 3)] =
                        make_uint4(p0, p1, p2, p3);
                }
            }
            __syncthreads();               // B3: wS staged

            // ---- MFMA: hw_g[j, c] = h[j,:] . Wg[:, c] ----
            {
                f32x4 acc[4];
#pragma unroll
                for (int ni = 0; ni < 4; ++ni) acc[ni] = (f32x4){0.f, 0.f, 0.f, 0.f};
#pragma unroll
                for (int st4 = 0; st4 < 4; ++st4) {
                    bf16x8 bfrag[4];
#pragma unroll
                    for (int ni = 0; ni < 4; ++ni)
                        bfrag[ni] = *(const bf16x8*)&LDS[8192 + (ni * 16 + l15) * 128 +
                                                         (((st4 * 4 + q) ^ l15) << 3)];
#pragma unroll
                    for (int ni = 0; ni < 4; ++ni)
                        acc[ni] = __builtin_amdgcn_mfma_f32_16x16x32_bf16(
                            af[st4], bfrag[ni], acc[ni], 0, 0, 0);
                }
                // epilogue -> hwS slot t; store c at oct^t swizzle
#pragma unroll
                for (int ni = 0; ni < 4; ++ni) {
                    int c = ni * 16 + l15;
                    int o = c >> 3;
                    int cpos = ((o ^ t) << 3) + (c & 7);
#pragma unroll
                    for (int r = 0; r < 4; ++r) {
                        int jrow = wv * 16 + q * 4 + r;
                        LDS[16384 + t * 4096 + jrow * 64 + cpos] = f2bf(acc[ni][r]);
                    }
                }
            }
            __syncthreads();               // B4: epilogue done, wS reusable
        }

        // ---- pool-accumulate this batch: out[i,c] += hw[j, g(i,j), c] ----
#pragma unroll
        for (int p = 0; p < 16; ++p) {
            u32 gu = gr[p];
#pragma unroll
            for (int b = 0; b < 4; ++b) {
                int j = p * 4 + b;
                int g = (int)(signed char)(gu >> (b * 8));
                if (g >= 0) {
                    int slot = __popc(mask & ((1u << g) - 1u));
                    if ((slot >> 2) == bi) {
                        int st = slot & 3;
                        const u16* hb_ = &LDS[16384 + st * 4096 + j * 64];
                        uint4 r0 = *(const uint4*)(hb_ + ((jo ^ st) << 3));
                        uint4 r1 = *(const uint4*)(hb_ + (((jo + 4) ^ st) << 3));
                        a0[0] += bflo(r0.x); a0[1] += bfhi(r0.x);
                        a0[2] += bflo(r0.y); a0[3] += bfhi(r0.y);
                        a0[4] += bflo(r0.z); a0[5] += bfhi(r0.z);
                        a0[6] += bflo(r0.w); a0[7] += bfhi(r0.w);
                        a1[0] += bflo(r1.x); a1[1] += bfhi(r1.x);
                        a1[2] += bflo(r1.y); a1[3] += bfhi(r1.y);
                        a1[4] += bflo(r1.z); a1[5] += bfhi(r1.z);
                        a1[6] += bflo(r1.w); a1[7] += bfhi(r1.w);
                    }
                }
            }
        }
        __syncthreads();                   // B5: pool done before next batch
        ++bi;
    }

    // ---- output: thread owns (i, octs jo and jo+4) ----
    const size_t orow = ((size_t)s * PEDS + i) * POOL;
    {
        int oc = jo * 8;
        float4 bb0 = *(const float4*)&bias[oc];
        float4 bb1 = *(const float4*)&bias[oc + 4];
        *(float4*)&out[orow + oc] =
            make_float4(a0[0] + bb0.x, a0[1] + bb0.y, a0[2] + bb0.z, a0[3] + bb0.w);
        *(float4*)&out[orow + oc + 4] =
            make_float4(a0[4] + bb1.x, a0[5] + bb1.y, a0[6] + bb1.z, a0[7] + bb1.w);
    }
    {
        int oc = (jo + 4) * 8;
        float4 bb0 = *(const float4*)&bias[oc];
        float4 bb1 = *(const float4*)&bias[oc + 4];
        *(float4*)&out[orow + oc] =
            make_float4(a1[0] + bb0.x, a1[1] + bb0.y, a1[2] + bb0.z, a1[3] + bb0.w);
        *(float4*)&out[orow + oc + 4] =
            make_float4(a1[4] + bb1.x, a1[5] + bb1.y, a1[6] + bb1.z, a1[7] + bb1.w);
    }
}

extern "C" void kernel_launch(void* const* d_in, const int* in_sizes, int n_in,
                              void* d_out, int out_size, void* d_ws, size_t ws_size,
                              hipStream_t stream) {
    const float* h    = (const float*)d_in[0];
    const float* pos  = (const float*)d_in[1];
    const float* w    = (const float*)d_in[2];
    const float* bias = (const float*)d_in[3];
    float* out = (float*)d_out;

    const int total = in_sizes[0] / HIDDEN;
    const int B     = total / PEDS;

    hipLaunchKernelGGL(social_pool_fused, dim3(B), dim3(256), 0, stream,
                       h, pos, w, bias, out);
}

// Round 3
// 70.426 us; speedup vs baseline: 1.5285x; 1.1633x over previous
//
#include <hip/hip_runtime.h>
#include <cstdint>

#define PEDS   64
#define HIDDEN 128
#define POOL   64
#define GRIDG  4
#define NBHD   2.0f

typedef unsigned short u16;
typedef unsigned int   u32;
typedef __attribute__((ext_vector_type(8))) short bf16x8;
typedef __attribute__((ext_vector_type(4))) float f32x4;

__device__ __forceinline__ u16 f2bf(float f) {
    u32 u = __float_as_uint(f);
    u += 0x7fffu + ((u >> 16) & 1u);   // RNE
    return (u16)(u >> 16);
}
__device__ __forceinline__ u32 pack2bf(float a, float b) {
    return (u32)f2bf(a) | ((u32)f2bf(b) << 16);
}

// One block per scene, 512 threads (8 waves, 2 waves/SIMD).
// Wave wv: m-tile mt=wv&3 (16 rows), n-half nh=wv>>2 (32 cols).
// out = sum_g M_g @ (h @ W_g), M_g[i,j] = (gidx[i,j]==g)  -- both matmuls MFMA.
// LDS 64KB: gidx[64x64] 4K | wmask | hA bf16[64][128] 16K |
//           wS bf16[2][64][128] 32K | hwT bf16[64][64] 8K
__global__ __launch_bounds__(512) void social_fused(
    const float* __restrict__ h, const float* __restrict__ pos,
    const float* __restrict__ w, const float* __restrict__ bias,
    float* __restrict__ out)
{
    __shared__ unsigned char LB[65536];
    unsigned char* gidx  = LB;                    // [0, 4096)
    u32*           wmask = (u32*)(LB + 4096);     // 8 words
    u16*           hA    = (u16*)(LB + 8192);     // [8192, 24576)
    u16*           hwT   = (u16*)(LB + 57344);    // [57344, 65536)

    const int s    = blockIdx.x;
    const int tid  = threadIdx.x;
    const int wv   = tid >> 6;
    const int lane = tid & 63;
    const int l15  = lane & 15;
    const int q    = lane >> 4;
    const int mt   = wv & 3;
    const int nh   = wv >> 2;

    // positions: each wave's lane l holds ped l
    float2 pp = ((const float2*)pos)[(size_t)s * PEDS + lane];
    float px = pp.x, py = pp.y;

    // h load: row = tid>>3, 16 floats at (tid&7)*16
    const int hrow = tid >> 3, hc = tid & 7;
    const float4* hsrc = (const float4*)(h + ((size_t)s * PEDS + hrow) * HIDDEN + hc * 16);
    float4 hv0 = hsrc[0], hv1 = hsrc[1], hv2 = hsrc[2], hv3 = hsrc[3];

    // gidx: i = wv*8 + (lane>>3); j = (lane&7)*8 + u
    const int gi  = wv * 8 + (lane >> 3);
    const int gj0 = (lane & 7) * 8;
    const float pxi = __shfl(px, gi), pyi = __shfl(py, gi);
    u32 gpk0 = 0, gpk1 = 0, um = 0;
    const float scale = (float)GRIDG / (2.0f * NBHD);
#pragma unroll
    for (int u8 = 0; u8 < 8; ++u8) {
        int j = gj0 + u8;
        float rx = __shfl(px, j) - pxi;
        float ry = __shfl(py, j) - pyi;
        u32 gb = 0xffu;
        if ((gi != j) && (fabsf(rx) <= NBHD) && (fabsf(ry) <= NBHD)) {
            int gx = (int)floorf((rx + NBHD) * scale); gx = min(max(gx, 0), GRIDG - 1);
            int gy = (int)floorf((ry + NBHD) * scale); gy = min(max(gy, 0), GRIDG - 1);
            int g = gy * GRIDG + gx;
            gb = (u32)g; um |= 1u << g;
        }
        if (u8 < 4) gpk0 |= gb << (u8 * 8); else gpk1 |= gb << ((u8 - 4) * 8);
    }
    *(uint2*)&gidx[gi * 64 + gj0] = make_uint2(gpk0, gpk1);

    // per-wave OR-reduce of used-cell mask; no atomics, no extra barrier
#pragma unroll
    for (int off = 32; off; off >>= 1) um |= __shfl_xor(um, off);
    if (lane == 0) wmask[wv] = um;

    // hA: bf16 convert, chunk c stored at c ^ (row&15)
    {
        u32 p0 = pack2bf(hv0.x, hv0.y), p1 = pack2bf(hv0.z, hv0.w);
        u32 p2 = pack2bf(hv1.x, hv1.y), p3 = pack2bf(hv1.z, hv1.w);
        int ch = hc * 2;
        *(uint4*)&hA[hrow * 128 + ((ch ^ (hrow & 15)) << 3)] = make_uint4(p0, p1, p2, p3);
        p0 = pack2bf(hv2.x, hv2.y); p1 = pack2bf(hv2.z, hv2.w);
        p2 = pack2bf(hv3.x, hv3.y); p3 = pack2bf(hv3.z, hv3.w);
        ch = hc * 2 + 1;
        *(uint4*)&hA[hrow * 128 + ((ch ^ (hrow & 15)) << 3)] = make_uint4(p0, p1, p2, p3);
    }
    __syncthreads();                               // B1: gidx, wmask, hA visible

    u32 mask = wmask[0] | wmask[1] | wmask[2] | wmask[3]
             | wmask[4] | wmask[5] | wmask[6] | wmask[7];
    mask = __builtin_amdgcn_readfirstlane(mask);

    // A fragments (h rows of this wave's m-tile) -> registers; hA dead after
    bf16x8 af[4];
#pragma unroll
    for (int st4 = 0; st4 < 4; ++st4)
        af[st4] = *(const bf16x8*)&hA[(mt * 16 + l15) * 128 + (((st4 * 4 + q) ^ l15) << 3)];

    const int ng = __popc(mask);
    u32 rem = mask;
    int g = 0;
    if (rem) { g = __ffs(rem) - 1; rem &= rem - 1u; }

    // W prefetch: c = lane, k = wv*16 + e  (coalesced 256B rows)
    float wr[16];
    const int wc = lane, wk = wv * 16;
    if (ng) {
        const float* wsrc = w + ((size_t)g * HIDDEN + wk) * POOL + wc;
#pragma unroll
        for (int e = 0; e < 16; ++e) wr[e] = wsrc[(size_t)e * POOL];
    }

    f32x4 oacc[2];
    oacc[0] = (f32x4){0.f, 0.f, 0.f, 0.f};
    oacc[1] = (f32x4){0.f, 0.f, 0.f, 0.f};

    for (int t = 0; t < ng; ++t) {
        u16* wSb = (u16*)(LB + 24576 + ((t & 1) << 14));
        // stage current W from registers (swizzled)
#pragma unroll
        for (int cc = 0; cc < 2; ++cc) {
            u32 p0 = pack2bf(wr[cc * 8 + 0], wr[cc * 8 + 1]);
            u32 p1 = pack2bf(wr[cc * 8 + 2], wr[cc * 8 + 3]);
            u32 p2 = pack2bf(wr[cc * 8 + 4], wr[cc * 8 + 5]);
            u32 p3 = pack2bf(wr[cc * 8 + 6], wr[cc * 8 + 7]);
            int ch = wv * 2 + cc;
            *(uint4*)&wSb[wc * 128 + ((ch ^ (wc & 15)) << 3)] = make_uint4(p0, p1, p2, p3);
        }
        // prefetch next cell's W (hidden under GEMMs)
        int gn = -1;
        if (rem) { gn = __ffs(rem) - 1; rem &= rem - 1u; }
        if (gn >= 0) {
            const float* wsrc = w + ((size_t)gn * HIDDEN + wk) * POOL + wc;
#pragma unroll
            for (int e = 0; e < 16; ++e) wr[e] = wsrc[(size_t)e * POOL];
        }
        __syncthreads();      // A: wS[t&1] staged; all waves done with GEMM2(t-1)

        // GEMM1: hw_g[j,c] = h[j,:].W_g[:,c]; this wave: 16 j x 32 c
        f32x4 a1[2];
        a1[0] = (f32x4){0.f, 0.f, 0.f, 0.f};
        a1[1] = (f32x4){0.f, 0.f, 0.f, 0.f};
#pragma unroll
        for (int st4 = 0; st4 < 4; ++st4) {
            int chs = ((st4 * 4 + q) ^ l15) << 3;
            bf16x8 b0 = *(const bf16x8*)&wSb[(nh * 32 + l15) * 128 + chs];
            bf16x8 b1 = *(const bf16x8*)&wSb[(nh * 32 + 16 + l15) * 128 + chs];
            a1[0] = __builtin_amdgcn_mfma_f32_16x16x32_bf16(af[st4], b0, a1[0], 0, 0, 0);
            a1[1] = __builtin_amdgcn_mfma_f32_16x16x32_bf16(af[st4], b1, a1[1], 0, 0, 0);
        }
        // hwT[c][j] bf16, j-quad jq stored at jq ^ (c&15)
#pragma unroll
        for (int ni = 0; ni < 2; ++ni) {
            int c = nh * 32 + ni * 16 + l15;
            u32 lo = pack2bf(a1[ni][0], a1[ni][1]);
            u32 hi = pack2bf(a1[ni][2], a1[ni][3]);
            *(uint2*)&hwT[c * 64 + (((mt * 4 + q) ^ (c & 15)) << 2)] = make_uint2(lo, hi);
        }
        __syncthreads();      // B: hwT visible

        // GEMM2: oacc += M_g @ hw_g   (K=64, 2 k-steps)
#pragma unroll
        for (int kk = 0; kk < 2; ++kk) {
            uint2 gg = *(const uint2*)&gidx[(mt * 16 + l15) * 64 + kk * 32 + q * 8];
            union { u16 hx[8]; bf16x8 v; } mu;
#pragma unroll
            for (int b = 0; b < 4; ++b)
                mu.hx[b]     = (((gg.x >> (b * 8)) & 0xffu) == (u32)g) ? (u16)0x3F80 : (u16)0;
#pragma unroll
            for (int b = 0; b < 4; ++b)
                mu.hx[4 + b] = (((gg.y >> (b * 8)) & 0xffu) == (u32)g) ? (u16)0x3F80 : (u16)0;
#pragma unroll
            for (int ni = 0; ni < 2; ++ni) {
                int c = nh * 32 + ni * 16 + l15;
                int cs = c & 15;
                uint2 b0 = *(const uint2*)&hwT[c * 64 + (((kk * 8 + q * 2 + 0) ^ cs) << 2)];
                uint2 b1 = *(const uint2*)&hwT[c * 64 + (((kk * 8 + q * 2 + 1) ^ cs) << 2)];
                union { u32 u[4]; bf16x8 v; } bu;
                bu.u[0] = b0.x; bu.u[1] = b0.y; bu.u[2] = b1.x; bu.u[3] = b1.y;
                oacc[ni] = __builtin_amdgcn_mfma_f32_16x16x32_bf16(mu.v, bu.v, oacc[ni], 0, 0, 0);
            }
        }
        g = gn;
    }

    // epilogue: out[i,c] = oacc + bias; i = mt*16+q*4+r, c = nh*32+ni*16+l15
#pragma unroll
    for (int ni = 0; ni < 2; ++ni) {
        int c = nh * 32 + ni * 16 + l15;
        float bv = bias[c];
        size_t ob = ((size_t)s * PEDS + mt * 16 + q * 4) * POOL + c;
#pragma unroll
        for (int r = 0; r < 4; ++r)
            out[ob + (size_t)r * POOL] = oacc[ni][r] + bv;
    }
}

extern "C" void kernel_launch(void* const* d_in, const int* in_sizes, int n_in,
                              void* d_out, int out_size, void* d_ws, size_t ws_size,
                              hipStream_t stream) {
    const float* h    = (const float*)d_in[0];
    const float* pos  = (const float*)d_in[1];
    const float* w    = (const float*)d_in[2];
    const float* bias = (const float*)d_in[3];
    float* out = (float*)d_out;

    const int total = in_sizes[0] / HIDDEN;
    const int B     = total / PEDS;

    hipLaunchKernelGGL(social_fused, dim3(B), dim3(512), 0, stream,
                       h, pos, w, bias, out);
}